// Round 1
// baseline (2549.418 us; speedup 1.0000x reference)
//
#include <hip/hip_runtime.h>

#define N_NODES 50000
#define N_EDGES 400000
#define DIN     32
#define DH      128
#define DOUT    16
#define NB      2

// ---------------------------------------------------------------------------
// x = inputs @ win + bin       [N,32]x[32,128]
// one thread per output element; win rows coalesced, input row broadcast
__global__ void k_node_proj(const float* __restrict__ inp,
                            const float* __restrict__ win,
                            const float* __restrict__ bin,
                            float* __restrict__ x) {
    int gid = blockIdx.x * blockDim.x + threadIdx.x;
    if (gid >= N_NODES * DH) return;
    int n = gid >> 7;
    int h = gid & 127;
    float acc = bin[h];
    const float* row = inp + (size_t)n * DIN;
#pragma unroll
    for (int k = 0; k < DIN; ++k)
        acc = fmaf(row[k], win[k * DH + h], acc);
    x[gid] = acc;
}

// ---------------------------------------------------------------------------
// Shared GEMM tile: acc[4][4] += A[32 x K](lda=LDA, in LDS) @ W[K x 128](global,
// streamed through sW). Thread owns rows eB..eB+3, cols hB..hB+3.
// NOTE: first __syncthreads() also serves as the "A is ready" barrier.
template <int K, int LDA>
__device__ __forceinline__ void gemm_tile(const float* __restrict__ Wg,
                                          const float* sA_, float* sW,
                                          int tid, int eB, int hB,
                                          float acc[4][4]) {
    for (int kt = 0; kt < K; kt += 32) {
        __syncthreads();  // everyone done with previous sW contents / A writes
#pragma unroll
        for (int i = 0; i < 4; ++i) {
            int row = (tid >> 5) + i * 8;      // 0..31
            int col = (tid & 31) * 4;          // 0..124
            *(float4*)&sW[row * 128 + col] =
                *(const float4*)(Wg + (size_t)(kt + row) * 128 + col);
        }
        __syncthreads();
#pragma unroll
        for (int kk = 0; kk < 32; kk += 4) {
            float4 a[4];
#pragma unroll
            for (int i = 0; i < 4; ++i)
                a[i] = *(const float4*)&sA_[(eB + i) * LDA + kt + kk];
#pragma unroll
            for (int q = 0; q < 4; ++q) {
                float4 w = *(const float4*)&sW[(kk + q) * 128 + hB];
#pragma unroll
                for (int i = 0; i < 4; ++i) {
                    float av = (&a[i].x)[q];   // q is compile-time after unroll
                    acc[i][0] = fmaf(av, w.x, acc[i][0]);
                    acc[i][1] = fmaf(av, w.y, acc[i][1]);
                    acc[i][2] = fmaf(av, w.z, acc[i][2]);
                    acc[i][3] = fmaf(av, w.w, acc[i][3]);
                }
            }
        }
    }
}

#define ZERO_ACC(acc)                          \
    _Pragma("unroll") for (int i_ = 0; i_ < 4; ++i_) \
        _Pragma("unroll") for (int j_ = 0; j_ < 4; ++j_) acc[i_][j_] = 0.f;

// ---------------------------------------------------------------------------
// Fused edge MLP for one graph-block:
//   m0 = [x[src] | x[dst]]  (gathered to LDS)
//   m1 = relu(m0 @ w1a + b1a); m2 = relu(m1 @ w1b + b1b); m3 = m2 @ w1c + b1c
//   agg[dst] += m3  (atomic)
// 256 threads, 32 edges per workgroup.
__global__ void __launch_bounds__(256, 2) k_edge(
    const float* __restrict__ x,
    const int* __restrict__ srcI, const int* __restrict__ dstI,
    const float* __restrict__ w1a, const float* __restrict__ b1a,
    const float* __restrict__ w1b, const float* __restrict__ b1b,
    const float* __restrict__ w1c, const float* __restrict__ b1c,
    float* __restrict__ agg) {
    __shared__ float sM0[32 * 256];  // m0 (32KB); first 16KB reused as m2
    __shared__ float sM1[32 * 128];  // m1 (16KB)
    __shared__ float sW[32 * 128];   // weight k-tile (16KB)
    __shared__ int sSrc[32], sDst[32];

    int tid = threadIdx.x;
    int e0 = blockIdx.x * 32;
    if (tid < 32) {
        sSrc[tid] = srcI[e0 + tid];
        sDst[tid] = dstI[e0 + tid];
    }
    __syncthreads();

    int lane4 = (tid & 31) * 4;
    int rgrp  = tid >> 5;
    // gather 64 rows (32 src + 32 dst), one row per 32-thread group
#pragma unroll
    for (int r = 0; r < 8; ++r) {
        int rr = r * 8 + rgrp;           // 0..63
        int e  = rr & 31;
        int node = (rr < 32) ? sSrc[e] : sDst[e];
        float4 v = *(const float4*)(x + (size_t)node * DH + lane4);
        *(float4*)&sM0[e * 256 + ((rr < 32) ? 0 : 128) + lane4] = v;
    }
    // (gemm_tile's first barrier covers gather completion)

    int eB = rgrp * 4;
    int hB = lane4;
    float acc[4][4];

    // ---- layer 1: sM1 = relu(m0 @ w1a + b1a), K=256
    ZERO_ACC(acc);
    gemm_tile<256, 256>(w1a, sM0, sW, tid, eB, hB, acc);
    {
        float4 b = *(const float4*)(b1a + hB);
#pragma unroll
        for (int i = 0; i < 4; ++i) {
            float4 v;
            v.x = fmaxf(acc[i][0] + b.x, 0.f);
            v.y = fmaxf(acc[i][1] + b.y, 0.f);
            v.z = fmaxf(acc[i][2] + b.z, 0.f);
            v.w = fmaxf(acc[i][3] + b.w, 0.f);
            *(float4*)&sM1[(eB + i) * 128 + hB] = v;
        }
    }
    __syncthreads();

    // ---- layer 2: m2(=sM0) = relu(m1 @ w1b + b1b), K=128
    ZERO_ACC(acc);
    gemm_tile<128, 128>(w1b, sM1, sW, tid, eB, hB, acc);
    {
        float4 b = *(const float4*)(b1b + hB);
#pragma unroll
        for (int i = 0; i < 4; ++i) {
            float4 v;
            v.x = fmaxf(acc[i][0] + b.x, 0.f);
            v.y = fmaxf(acc[i][1] + b.y, 0.f);
            v.z = fmaxf(acc[i][2] + b.z, 0.f);
            v.w = fmaxf(acc[i][3] + b.w, 0.f);
            *(float4*)&sM0[(eB + i) * 128 + hB] = v;
        }
    }
    __syncthreads();

    // ---- layer 3: m3 = m2 @ w1c + b1c, K=128, atomic scatter to agg[dst]
    ZERO_ACC(acc);
    gemm_tile<128, 128>(w1c, sM0, sW, tid, eB, hB, acc);
    {
        float4 b = *(const float4*)(b1c + hB);
#pragma unroll
        for (int i = 0; i < 4; ++i) {
            float* ap = agg + (size_t)sDst[eB + i] * DH + hB;
            unsafeAtomicAdd(ap + 0, acc[i][0] + b.x);
            unsafeAtomicAdd(ap + 1, acc[i][1] + b.y);
            unsafeAtomicAdd(ap + 2, acc[i][2] + b.z);
            unsafeAtomicAdd(ap + 3, acc[i][3] + b.w);
        }
    }
}

// ---------------------------------------------------------------------------
// Fused node MLP for one graph-block: x = relu(agg@w2a + b2a) @ w2b + b2b
// 256 threads, 32 nodes per workgroup.
__global__ void __launch_bounds__(256, 2) k_node(
    const float* __restrict__ agg,
    const float* __restrict__ w2a, const float* __restrict__ b2a,
    const float* __restrict__ w2b, const float* __restrict__ b2b,
    float* __restrict__ xo) {
    __shared__ float sA[32 * 128];
    __shared__ float sB[32 * 128];
    __shared__ float sW[32 * 128];

    int tid = threadIdx.x;
    int n0 = blockIdx.x * 32;
    int lane4 = (tid & 31) * 4;
    int rgrp  = tid >> 5;
#pragma unroll
    for (int r = 0; r < 4; ++r) {
        int rr = r * 8 + rgrp;  // 0..31
        int n = n0 + rr;
        float4 v = make_float4(0.f, 0.f, 0.f, 0.f);
        if (n < N_NODES) v = *(const float4*)(agg + (size_t)n * DH + lane4);
        *(float4*)&sA[rr * 128 + lane4] = v;
    }

    int eB = rgrp * 4;
    int hB = lane4;
    float acc[4][4];

    ZERO_ACC(acc);
    gemm_tile<128, 128>(w2a, sA, sW, tid, eB, hB, acc);
    {
        float4 b = *(const float4*)(b2a + hB);
#pragma unroll
        for (int i = 0; i < 4; ++i) {
            float4 v;
            v.x = fmaxf(acc[i][0] + b.x, 0.f);
            v.y = fmaxf(acc[i][1] + b.y, 0.f);
            v.z = fmaxf(acc[i][2] + b.z, 0.f);
            v.w = fmaxf(acc[i][3] + b.w, 0.f);
            *(float4*)&sB[(eB + i) * 128 + hB] = v;
        }
    }
    __syncthreads();

    ZERO_ACC(acc);
    gemm_tile<128, 128>(w2b, sB, sW, tid, eB, hB, acc);
    {
        float4 b = *(const float4*)(b2b + hB);
#pragma unroll
        for (int i = 0; i < 4; ++i) {
            int n = n0 + eB + i;
            if (n < N_NODES) {
                float4 v;
                v.x = acc[i][0] + b.x;
                v.y = acc[i][1] + b.y;
                v.z = acc[i][2] + b.z;
                v.w = acc[i][3] + b.w;
                *(float4*)(xo + (size_t)n * DH + hB) = v;
            }
        }
    }
}

// ---------------------------------------------------------------------------
// out = x @ wout + bout      [N,128]x[128,16]
__global__ void k_out(const float* __restrict__ x,
                      const float* __restrict__ wout,
                      const float* __restrict__ bout,
                      float* __restrict__ out) {
    int gid = blockIdx.x * blockDim.x + threadIdx.x;
    if (gid >= N_NODES * DOUT) return;
    int n = gid >> 4;
    int o = gid & 15;
    float acc = bout[o];
    const float* row = x + (size_t)n * DH;
#pragma unroll 8
    for (int k = 0; k < DH; ++k)
        acc = fmaf(row[k], wout[k * DOUT + o], acc);
    out[gid] = acc;
}

// ---------------------------------------------------------------------------
extern "C" void kernel_launch(void* const* d_in, const int* in_sizes, int n_in,
                              void* d_out, int out_size, void* d_ws, size_t ws_size,
                              hipStream_t stream) {
    const float* inputs = (const float*)d_in[0];
    // d_in[1] = frames : UNUSED by reference
    const int* eidx = (const int*)d_in[2];
    const int* srcI = eidx;             // edge_index[0] : message source j
    const int* dstI = eidx + N_EDGES;   // edge_index[1] : aggregation target i
    const float* win  = (const float*)d_in[3];
    const float* bin_ = (const float*)d_in[4];
    const float* wout = (const float*)d_in[5];
    const float* bout = (const float*)d_in[6];
    const float* w1a = (const float*)d_in[7];
    const float* b1a = (const float*)d_in[8];
    const float* w1b = (const float*)d_in[9];
    const float* b1b = (const float*)d_in[10];
    const float* w1c = (const float*)d_in[11];
    const float* b1c = (const float*)d_in[12];
    const float* w2a = (const float*)d_in[13];
    const float* b2a = (const float*)d_in[14];
    const float* w2b = (const float*)d_in[15];
    const float* b2b = (const float*)d_in[16];

    float* x   = (float*)d_ws;                     // [N,128] fp32
    float* agg = x + (size_t)N_NODES * DH;         // [N,128] fp32
    float* out = (float*)d_out;

    k_node_proj<<<(N_NODES * DH + 255) / 256, 256, 0, stream>>>(inputs, win, bin_, x);

    for (int b = 0; b < NB; ++b) {
        hipMemsetAsync(agg, 0, (size_t)N_NODES * DH * sizeof(float), stream);
        k_edge<<<N_EDGES / 32, 256, 0, stream>>>(
            x, srcI, dstI,
            w1a + (size_t)b * 2 * DH * DH, b1a + (size_t)b * DH,
            w1b + (size_t)b * DH * DH,     b1b + (size_t)b * DH,
            w1c + (size_t)b * DH * DH,     b1c + (size_t)b * DH,
            agg);
        k_node<<<(N_NODES + 31) / 32, 256, 0, stream>>>(
            agg,
            w2a + (size_t)b * DH * DH, b2a + (size_t)b * DH,
            w2b + (size_t)b * DH * DH, b2b + (size_t)b * DH,
            x);
    }

    k_out<<<(N_NODES * DOUT + 255) / 256, 256, 0, stream>>>(x, wout, bout, out);
}

// Round 2
// 597.259 us; speedup vs baseline: 4.2685x; 4.2685x over previous
//
#include <hip/hip_runtime.h>

#define N_NODES 50000
#define N_EDGES 400000
#define DIN     32
#define DH      128
#define DOUT    16
#define NB      2

typedef _Float16 half8 __attribute__((ext_vector_type(8)));
typedef _Float16 half4 __attribute__((ext_vector_type(4)));
typedef float    f32x4 __attribute__((ext_vector_type(4)));

// ---------------------------------------------------------------------------
// x16 = f16(inputs @ win + bin)       [N,32]x[32,128]
__global__ void k_node_proj(const float* __restrict__ inp,
                            const float* __restrict__ win,
                            const float* __restrict__ bin,
                            _Float16* __restrict__ x16) {
    int gid = blockIdx.x * blockDim.x + threadIdx.x;
    if (gid >= N_NODES * DH) return;
    int n = gid >> 7;
    int h = gid & 127;
    float acc = bin[h];
    const float* row = inp + (size_t)n * DIN;
#pragma unroll
    for (int k = 0; k < DIN; ++k)
        acc = fmaf(row[k], win[k * DH + h], acc);
    x16[gid] = (_Float16)acc;
}

// ---------------------------------------------------------------------------
// Pre-permute edge-MLP weights into fragment-linear f16.
// Chunk layout per graph-block b (8192 chunks of 8 f16 = 16B):
//   [0,4096)    w1a  (K=256, t=0..7)
//   [4096,6144) w1b  (K=128, t=0..3)
//   [6144,8192) w1c  (K=128, t=0..3)
// chunk r (within matrix) = (t*8 + n)*64 + l ; elem j holds
//   W[t*32 + (l>>4)*8 + j][n*16 + (l&15)]
__global__ void k_wprep(const float* __restrict__ w1a,
                        const float* __restrict__ w1b,
                        const float* __restrict__ w1c,
                        _Float16* __restrict__ wf) {
    int c = blockIdx.x * blockDim.x + threadIdx.x;
    if (c >= NB * 8192) return;
    int b = c >> 13;
    int r = c & 8191;
    const float* W;
    int t;
    if (r < 4096)      { W = w1a + (size_t)b * 2 * DH * DH; t = r >> 9; }
    else if (r < 6144) { W = w1b + (size_t)b * DH * DH;     t = (r - 4096) >> 9; }
    else               { W = w1c + (size_t)b * DH * DH;     t = (r - 6144) >> 9; }
    int n = (r >> 6) & 7;   // 4096/6144 are multiples of 512 & 64, so bits line up
    int l = r & 63;
    int row0 = t * 32 + (l >> 4) * 8;
    int col  = n * 16 + (l & 15);
    half8 v;
#pragma unroll
    for (int j = 0; j < 8; ++j)
        v[j] = (_Float16)W[(size_t)(row0 + j) * DH + col];
    *(half8*)(wf + (size_t)c * 8) = v;
}

// ---------------------------------------------------------------------------
// Fused edge MLP, f16 MFMA. 4 waves x 16 edges = 64 edges/wg.
// Per wave: A-frags gathered from x16 (layer1) or private LDS m-buffer
// (layers 2,3); B-frags from fragment-linear weights (L2-hot); C/D layout:
// row(edge)=(l>>4)*4+reg, col(feat)=l&15  [HW-verified mapping].
__global__ void __launch_bounds__(256) k_edge_mfma(
    const _Float16* __restrict__ x16,
    const int* __restrict__ srcI, const int* __restrict__ dstI,
    const half8* __restrict__ wfa, const half8* __restrict__ wfb,
    const half8* __restrict__ wfc,
    const float* __restrict__ b1a, const float* __restrict__ b1b,
    const float* __restrict__ b1c,
    float* __restrict__ agg) {
    __shared__ _Float16 sM[4][2048];   // per-wave 4KB fragment buffer (m1/m2)

    const int tid = threadIdx.x;
    const int wv  = tid >> 6;
    const int l   = tid & 63;
    const int lm  = l & 15;            // A row / C col slot
    const int lk  = l >> 4;            // k-group
    const int e0  = blockIdx.x * 64 + wv * 16;

    const int eA = e0 + lm;
    const int sA = srcI[eA];
    const int dA = dstI[eA];

    float ba[8], bb[8], bc[8];
#pragma unroll
    for (int n = 0; n < 8; ++n) {
        ba[n] = b1a[n * 16 + lm];
        bb[n] = b1b[n * 16 + lm];
        bc[n] = b1c[n * 16 + lm];
    }

    _Float16* sm = sM[wv];
    const f32x4 z = {0.f, 0.f, 0.f, 0.f};
    f32x4 acc[8];

    // ---- layer 1: K=256 (k 0..127 from x[src], 128..255 from x[dst])
#pragma unroll
    for (int n = 0; n < 8; ++n) acc[n] = z;
    for (int t = 0; t < 8; ++t) {
        const _Float16* ap =
            x16 + (size_t)(t < 4 ? sA : dA) * DH + (t & 3) * 32 + lk * 8;
        half8 af = *(const half8*)ap;
        const half8* wp = wfa + (size_t)t * 512 + l;
#pragma unroll
        for (int n = 0; n < 8; ++n)
            acc[n] = __builtin_amdgcn_mfma_f32_16x16x32_f16(af, wp[n * 64],
                                                            acc[n], 0, 0, 0);
    }
    // epilogue 1: bias+relu -> m1 fragments in LDS
    // value (e = lk*4+j, f = n*16+lm) -> addr (t=f>>5, kg=(f>>3)&3, s=e, elem=f&7)
#pragma unroll
    for (int n = 0; n < 8; ++n) {
        int base = ((n >> 1) * 64 + ((n & 1) * 2 + (lm >> 3)) * 16 + lk * 4) * 8
                   + (lm & 7);
#pragma unroll
        for (int j = 0; j < 4; ++j)
            sm[base + j * 8] = (_Float16)fmaxf(acc[n][j] + ba[n], 0.f);
    }
    __syncthreads();

    // ---- layer 2: K=128, A from LDS (linear per-lane 16B reads)
#pragma unroll
    for (int n = 0; n < 8; ++n) acc[n] = z;
    for (int t = 0; t < 4; ++t) {
        half8 af = *(const half8*)&sm[(t * 64 + l) * 8];
        const half8* wp = wfb + (size_t)t * 512 + l;
#pragma unroll
        for (int n = 0; n < 8; ++n)
            acc[n] = __builtin_amdgcn_mfma_f32_16x16x32_f16(af, wp[n * 64],
                                                            acc[n], 0, 0, 0);
    }
    __syncthreads();   // all m1 reads done before overwrite
    // epilogue 2: bias+relu -> m2 (same buffer)
#pragma unroll
    for (int n = 0; n < 8; ++n) {
        int base = ((n >> 1) * 64 + ((n & 1) * 2 + (lm >> 3)) * 16 + lk * 4) * 8
                   + (lm & 7);
#pragma unroll
        for (int j = 0; j < 4; ++j)
            sm[base + j * 8] = (_Float16)fmaxf(acc[n][j] + bb[n], 0.f);
    }
    __syncthreads();

    // ---- layer 3: K=128, atomic scatter epilogue
#pragma unroll
    for (int n = 0; n < 8; ++n) acc[n] = z;
    for (int t = 0; t < 4; ++t) {
        half8 af = *(const half8*)&sm[(t * 64 + l) * 8];
        const half8* wp = wfc + (size_t)t * 512 + l;
#pragma unroll
        for (int n = 0; n < 8; ++n)
            acc[n] = __builtin_amdgcn_mfma_f32_16x16x32_f16(af, wp[n * 64],
                                                            acc[n], 0, 0, 0);
    }
    int ed[4];
#pragma unroll
    for (int j = 0; j < 4; ++j) ed[j] = dstI[e0 + lk * 4 + j];
#pragma unroll
    for (int n = 0; n < 8; ++n) {
#pragma unroll
        for (int j = 0; j < 4; ++j)
            unsafeAtomicAdd(agg + (size_t)ed[j] * DH + n * 16 + lm,
                            acc[n][j] + bc[n]);
    }
}

// ---------------------------------------------------------------------------
// fp32 tiled GEMM helper (kept for node MLP — known-correct from round 1)
template <int K, int LDA>
__device__ __forceinline__ void gemm_tile(const float* __restrict__ Wg,
                                          const float* sA_, float* sW,
                                          int tid, int eB, int hB,
                                          float acc[4][4]) {
    for (int kt = 0; kt < K; kt += 32) {
        __syncthreads();
#pragma unroll
        for (int i = 0; i < 4; ++i) {
            int row = (tid >> 5) + i * 8;
            int col = (tid & 31) * 4;
            *(float4*)&sW[row * 128 + col] =
                *(const float4*)(Wg + (size_t)(kt + row) * 128 + col);
        }
        __syncthreads();
#pragma unroll
        for (int kk = 0; kk < 32; kk += 4) {
            float4 a[4];
#pragma unroll
            for (int i = 0; i < 4; ++i)
                a[i] = *(const float4*)&sA_[(eB + i) * LDA + kt + kk];
#pragma unroll
            for (int q = 0; q < 4; ++q) {
                float4 w = *(const float4*)&sW[(kk + q) * 128 + hB];
#pragma unroll
                for (int i = 0; i < 4; ++i) {
                    float av = (&a[i].x)[q];
                    acc[i][0] = fmaf(av, w.x, acc[i][0]);
                    acc[i][1] = fmaf(av, w.y, acc[i][1]);
                    acc[i][2] = fmaf(av, w.z, acc[i][2]);
                    acc[i][3] = fmaf(av, w.w, acc[i][3]);
                }
            }
        }
    }
}

#define ZERO_ACC(acc)                          \
    _Pragma("unroll") for (int i_ = 0; i_ < 4; ++i_) \
        _Pragma("unroll") for (int j_ = 0; j_ < 4; ++j_) acc[i_][j_] = 0.f;

// ---------------------------------------------------------------------------
// Node MLP: x16 = f16(relu(agg@w2a + b2a) @ w2b + b2b)
__global__ void __launch_bounds__(256, 2) k_node(
    const float* __restrict__ agg,
    const float* __restrict__ w2a, const float* __restrict__ b2a,
    const float* __restrict__ w2b, const float* __restrict__ b2b,
    _Float16* __restrict__ xo) {
    __shared__ float sA[32 * 128];
    __shared__ float sB[32 * 128];
    __shared__ float sW[32 * 128];

    int tid = threadIdx.x;
    int n0 = blockIdx.x * 32;
    int lane4 = (tid & 31) * 4;
    int rgrp  = tid >> 5;
#pragma unroll
    for (int r = 0; r < 4; ++r) {
        int rr = r * 8 + rgrp;
        int n = n0 + rr;
        float4 v = make_float4(0.f, 0.f, 0.f, 0.f);
        if (n < N_NODES) v = *(const float4*)(agg + (size_t)n * DH + lane4);
        *(float4*)&sA[rr * 128 + lane4] = v;
    }

    int eB = rgrp * 4;
    int hB = lane4;
    float acc[4][4];

    ZERO_ACC(acc);
    gemm_tile<128, 128>(w2a, sA, sW, tid, eB, hB, acc);
    {
        float4 b = *(const float4*)(b2a + hB);
#pragma unroll
        for (int i = 0; i < 4; ++i) {
            float4 v;
            v.x = fmaxf(acc[i][0] + b.x, 0.f);
            v.y = fmaxf(acc[i][1] + b.y, 0.f);
            v.z = fmaxf(acc[i][2] + b.z, 0.f);
            v.w = fmaxf(acc[i][3] + b.w, 0.f);
            *(float4*)&sB[(eB + i) * 128 + hB] = v;
        }
    }
    __syncthreads();

    ZERO_ACC(acc);
    gemm_tile<128, 128>(w2b, sB, sW, tid, eB, hB, acc);
    {
        float4 b = *(const float4*)(b2b + hB);
#pragma unroll
        for (int i = 0; i < 4; ++i) {
            int n = n0 + eB + i;
            if (n < N_NODES) {
                half4 h;
                h[0] = (_Float16)(acc[i][0] + b.x);
                h[1] = (_Float16)(acc[i][1] + b.y);
                h[2] = (_Float16)(acc[i][2] + b.z);
                h[3] = (_Float16)(acc[i][3] + b.w);
                *(half4*)&xo[(size_t)n * DH + hB] = h;
            }
        }
    }
}

// ---------------------------------------------------------------------------
// out = x16 @ wout + bout      [N,128]x[128,16]
__global__ void k_out(const _Float16* __restrict__ x16,
                      const float* __restrict__ wout,
                      const float* __restrict__ bout,
                      float* __restrict__ out) {
    int gid = blockIdx.x * blockDim.x + threadIdx.x;
    if (gid >= N_NODES * DOUT) return;
    int n = gid >> 4;
    int o = gid & 15;
    float acc = bout[o];
    const _Float16* row = x16 + (size_t)n * DH;
#pragma unroll 8
    for (int k = 0; k < DH; ++k)
        acc = fmaf((float)row[k], wout[k * DOUT + o], acc);
    out[gid] = acc;
}

// ---------------------------------------------------------------------------
extern "C" void kernel_launch(void* const* d_in, const int* in_sizes, int n_in,
                              void* d_out, int out_size, void* d_ws, size_t ws_size,
                              hipStream_t stream) {
    const float* inputs = (const float*)d_in[0];
    // d_in[1] = frames : UNUSED by reference
    const int* eidx = (const int*)d_in[2];
    const int* srcI = eidx;
    const int* dstI = eidx + N_EDGES;
    const float* win  = (const float*)d_in[3];
    const float* bin_ = (const float*)d_in[4];
    const float* wout = (const float*)d_in[5];
    const float* bout = (const float*)d_in[6];
    const float* w1a = (const float*)d_in[7];
    const float* b1a = (const float*)d_in[8];
    const float* w1b = (const float*)d_in[9];
    const float* b1b = (const float*)d_in[10];
    const float* w1c = (const float*)d_in[11];
    const float* b1c = (const float*)d_in[12];
    const float* w2a = (const float*)d_in[13];
    const float* b2a = (const float*)d_in[14];
    const float* w2b = (const float*)d_in[15];
    const float* b2b = (const float*)d_in[16];

    // ws layout: x16 [N*128 f16] | agg [N*128 f32] | wfrag [NB*8192*8 f16]
    const size_t X16_BYTES = (size_t)N_NODES * DH * sizeof(_Float16);  // 12.8MB
    const size_t AGG_BYTES = (size_t)N_NODES * DH * sizeof(float);     // 25.6MB
    _Float16* x16 = (_Float16*)d_ws;
    float*    agg = (float*)((char*)d_ws + X16_BYTES);
    _Float16* wf  = (_Float16*)((char*)d_ws + X16_BYTES + AGG_BYTES);  // 256KB
    float* out = (float*)d_out;

    k_wprep<<<(NB * 8192 + 255) / 256, 256, 0, stream>>>(w1a, w1b, w1c, wf);
    k_node_proj<<<(N_NODES * DH + 255) / 256, 256, 0, stream>>>(inputs, win, bin_, x16);

    for (int b = 0; b < NB; ++b) {
        hipMemsetAsync(agg, 0, AGG_BYTES, stream);
        const half8* wfa = (const half8*)(wf + (size_t)b * 8192 * 8);
        const half8* wfb = wfa + 4096;
        const half8* wfc = wfa + 6144;
        k_edge_mfma<<<N_EDGES / 64, 256, 0, stream>>>(
            x16, srcI, dstI, wfa, wfb, wfc,
            b1a + (size_t)b * DH, b1b + (size_t)b * DH, b1c + (size_t)b * DH,
            agg);
        k_node<<<(N_NODES + 31) / 32, 256, 0, stream>>>(
            agg,
            w2a + (size_t)b * DH * DH, b2a + (size_t)b * DH,
            w2b + (size_t)b * DH * DH, b2b + (size_t)b * DH,
            x16);
    }

    k_out<<<(N_NODES * DOUT + 255) / 256, 256, 0, stream>>>(x16, wout, bout, out);
}